// Round 7
// baseline (230.812 us; speedup 1.0000x reference)
//
#include <hip/hip_runtime.h>
#include <hip/hip_bf16.h>

// Problem constants (fixed by setup_inputs)
constexpr int B = 4, Q = 100, C = 40, Cp1 = 41, HW = 65536;
constexpr int NPIX = B * HW;          // 262144

// kA geometry: 4 px/thread (float4), 128 thr -> 512 blocks, 10-deep load batch
constexpr int APXT = 4, ATHR = 128;
constexpr int ABLK = NPIX / (APXT * ATHR);   // 512
constexpr int SLOT = ABLK / B;               // 128
constexpr int QU = 10;                       // q-loop load batch depth

// kB geometry: 128 thr, 8 chunks -> 3200 blocks, hist 20 KB -> 8 blocks/CU
constexpr int BTHR = 128, BCHUNKS = 8;
constexpr int BCPX = HW / BCHUNKS;           // 8192 px/block
constexpr int BITERS = BCPX / (BTHR * 4);    // 16

// Workspace layout (4-byte words) — verified R4 layout
//  [0, 16000)      counts  u32 [B][Q][C]
//  [16000, 16160)  tsum    u32 [B][C]
//  [16160, 32160)  inter   f32 [B][Q][C]
//  [32160, 32560)  src_sum f32 [B][Q]
//  [32560]         ce_sum  f32
//  [32561]         n_valid u32
constexpr int WS_WORDS = 32562;

__global__ void kZ(unsigned* __restrict__ ws, int n) {
    int i = blockIdx.x * blockDim.x + threadIdx.x;
    for (; i < n; i += gridDim.x * blockDim.x) ws[i] = 0u;
}

// Kernel A: pixel-major. 4 px/thread; 10 float4 loads batched in registers
// per q-group (160 B/lane in flight) to cover HBM latency.
// Plain sum-exp LSE (|v|<=~6, f32-safe); running max only for argmax.
__global__ __launch_bounds__(ATHR) void kA(const float* __restrict__ masks,
                                           const int* __restrict__ targets,
                                           unsigned* __restrict__ counts,
                                           unsigned* __restrict__ tsum,
                                           float* __restrict__ ce_sum,
                                           unsigned* __restrict__ n_valid) {
    int tid = threadIdx.x;
    int blk = blockIdx.x;
    int b = blk / SLOT;
    int hw = (blk % SLOT) * (ATHR * APXT) + tid * APXT;
    const float* mp = masks + (size_t)b * Q * HW + hw;
    int4 tg = *(const int4*)(targets + (size_t)b * HW + hw);
    int tgs[4] = {tg.x, tg.y, tg.z, tg.w};

    float m[4] = {-INFINITY, -INFINITY, -INFINITY, -INFINITY};
    float s[4] = {0.f, 0.f, 0.f, 0.f};
    float xt[4] = {0.f, 0.f, 0.f, 0.f};
    int amax[4] = {0, 0, 0, 0};

    for (int qq = 0; qq < Q; qq += QU) {
        float4 vv[QU];
        #pragma unroll
        for (int u = 0; u < QU; ++u)
            vv[u] = *(const float4*)(mp + (size_t)(qq + u) * HW);
        #pragma unroll
        for (int u = 0; u < QU; ++u) {
            int q = qq + u;
            float v[4] = {vv[u].x, vv[u].y, vv[u].z, vv[u].w};
            #pragma unroll
            for (int j = 0; j < 4; ++j) {
                s[j] += __expf(v[j]);
                amax[j] = (v[j] > m[j]) ? q : amax[j];   // strict >: first max
                m[j] = fmaxf(m[j], v[j]);
                xt[j] = (q == tgs[j]) ? v[j] : xt[j];
            }
        }
    }

    __shared__ unsigned ts_local[C];
    __shared__ float cred[2];
    __shared__ unsigned vred[2];
    if (tid < C) ts_local[tid] = 0u;
    __syncthreads();

    float ce = 0.f;
    unsigned nv = 0;
    #pragma unroll
    for (int j = 0; j < 4; ++j) {
        if (tgs[j] != 255) {                              // valid; in [0,40)
            ce += __logf(s[j]) - xt[j];
            nv++;
            atomicAdd(&counts[((size_t)b * Q + amax[j]) * C + tgs[j]], 1u);
            atomicAdd(&ts_local[tgs[j]], 1u);
        }
    }

    for (int off = 32; off; off >>= 1) {
        ce += __shfl_xor(ce, off);
        nv += __shfl_xor(nv, off);
    }
    int lane = tid & 63, wave = tid >> 6;
    if (lane == 0) { cred[wave] = ce; vred[wave] = nv; }
    __syncthreads();
    if (tid == 0) {
        atomicAdd(ce_sum, cred[0] + cred[1]);
        atomicAdd(n_valid, vred[0] + vred[1]);
    }
    if (tid < C) {
        unsigned t = ts_local[tid];
        if (t) atomicAdd(&tsum[b * C + tid], t);
    }
}

// Kernel B: (b,q)-major. Per-thread LDS hist columns (conflict-free: word
// index c*128+tid -> bank tid%32). 20 KB LDS -> 8 blocks/CU.
__global__ __launch_bounds__(BTHR) void kB(const float* __restrict__ masks,
                                           const int* __restrict__ targets,
                                           float* __restrict__ inter,
                                           float* __restrict__ src_sum) {
    __shared__ float hist[C][BTHR];   // 20 KB
    int tid = threadIdx.x;
    int bq = blockIdx.x >> 3;         // / BCHUNKS
    int chunk = blockIdx.x & 7;
    int b = bq / Q;
    const float* mp = masks + (size_t)bq * HW + chunk * BCPX;
    const int* tp = targets + (size_t)b * HW + chunk * BCPX;

    #pragma unroll
    for (int c = 0; c < C; ++c) hist[c][tid] = 0.f;   // own column only

    float sacc = 0.f;
    #pragma unroll 4
    for (int it = 0; it < BITERS; ++it) {              // 16 iters * 512 px
        int off = it * (BTHR * 4) + tid * 4;
        float4 x = *(const float4*)(mp + off);
        int4 tg = *(const int4*)(tp + off);
        float xs[4] = {x.x, x.y, x.z, x.w};
        int cs[4] = {tg.x, tg.y, tg.z, tg.w};
        #pragma unroll
        for (int j = 0; j < 4; ++j) {
            float sig = __builtin_amdgcn_rcpf(1.f + __expf(-xs[j]));
            sacc += sig;
            if ((unsigned)cs[j] < (unsigned)C) hist[cs[j]][tid] += sig;
        }
    }

    // src_sum: wave reduce + atomic
    for (int off = 32; off; off >>= 1) sacc += __shfl_xor(sacc, off);
    int lane = tid & 63, wave = tid >> 6;
    if (lane == 0) atomicAdd(&src_sum[bq], sacc);

    __syncthreads();
    // reduce hist columns: wave w handles 20 classes
    for (int c = wave * 20; c < wave * 20 + 20; ++c) {
        float h = hist[c][lane] + hist[c][lane + 64];
        for (int off = 32; off; off >>= 1) h += __shfl_xor(h, off);
        if (lane == 0) atomicAdd(&inter[(size_t)bq * C + c], h);
    }
}

// Kernel C: finalize. Single block. f32 scalar out. (Verified R4.)
__global__ __launch_bounds__(512) void kC(const float* __restrict__ logits,
                                          const unsigned* __restrict__ counts,
                                          const unsigned* __restrict__ tsum,
                                          const float* __restrict__ inter,
                                          const float* __restrict__ src_sum,
                                          const float* __restrict__ ce_sum,
                                          const unsigned* __restrict__ n_valid,
                                          float* __restrict__ out) {
    int tid = threadIdx.x;
    __shared__ float dice_sum[C];
    __shared__ float wred[8];
    __shared__ float s_lce;
    if (tid < C) dice_sum[tid] = 0.f;

    float ce_acc = 0.f;
    for (int i = tid; i < B * Q; i += 512) {
        const unsigned* cnt = counts + (size_t)i * C;
        unsigned best = 0;
        int tc = C;
        #pragma unroll
        for (int c = 0; c < C; ++c) {
            unsigned v = cnt[c];
            if (v > best) { best = v; tc = c; }
        }
        if (tc != C) {
            const float* lg = logits + (size_t)i * Cp1;
            float mm = -INFINITY, xt = 0.f;
            #pragma unroll
            for (int c = 0; c < Cp1; ++c) {
                float v = lg[c];
                mm = fmaxf(mm, v);
                if (c == tc) xt = v;
            }
            float ss = 0.f;
            #pragma unroll
            for (int c = 0; c < Cp1; ++c) ss += __expf(lg[c] - mm);
            float nll = mm + __logf(ss) - xt;
            float p = __expf(-nll);
            float om = 1.f - p;
            ce_acc += om * om * nll;
        }
    }
    for (int off = 32; off; off >>= 1) ce_acc += __shfl_xor(ce_acc, off);
    if ((tid & 63) == 0) wred[tid >> 6] = ce_acc;
    __syncthreads();
    if (tid == 0) {
        float t = 0.f;
        for (int w = 0; w < 8; ++w) t += wred[w];
        s_lce = t;
    }

    for (int i = tid; i < B * Q * C; i += 512) {
        int bq = i / C, c = i - bq * C;
        float denom = src_sum[bq] + (float)tsum[(bq / Q) * C + c] + 1e-8f;
        atomicAdd(&dice_sum[c], 2.f * inter[i] / denom);
    }
    __syncthreads();

    if (tid == 0) {
        float dl = 0.f;
        for (int c = 0; c < C; ++c) {
            unsigned ts = tsum[c] + tsum[C + c] + tsum[2 * C + c] + tsum[3 * C + c];
            if (ts > 0) dl += 1.f - dice_sum[c] * (1.f / (B * Q));
        }
        dl *= (1.f / C);
        float ce_mask = ce_sum[0] / fmaxf((float)n_valid[0], 1.f);
        float lce = s_lce * (1.f / (B * Q));
        out[0] = 2.f * lce + 5.f * ce_mask + 5.f * dl;
    }
}

extern "C" void kernel_launch(void* const* d_in, const int* in_sizes, int n_in,
                              void* d_out, int out_size, void* d_ws, size_t ws_size,
                              hipStream_t stream) {
    const float* logits  = (const float*)d_in[0];   // [B,Q,41] f32
    const float* masks   = (const float*)d_in[1];   // [B,Q,H,W] f32
    const int*   targets = (const int*)d_in[2];     // [B,H,W] int32
    float* out = (float*)d_out;                     // f32 scalar

    unsigned* ws      = (unsigned*)d_ws;
    unsigned* counts  = ws;                         // 16000 u32
    unsigned* tsum    = ws + 16000;                 // 160 u32
    float*    inter   = (float*)(ws + 16160);       // 16000 f32
    float*    src_sum = (float*)(ws + 32160);       // 400 f32
    float*    ce_sum  = (float*)(ws + 32560);       // 1 f32
    unsigned* n_valid = ws + 32561;                 // 1 u32

    kZ<<<64, 256, 0, stream>>>(ws, WS_WORDS);
    kA<<<ABLK, ATHR, 0, stream>>>(masks, targets, counts, tsum, ce_sum, n_valid);
    kB<<<B * Q * BCHUNKS, BTHR, 0, stream>>>(masks, targets, inter, src_sum);
    kC<<<1, 512, 0, stream>>>(logits, counts, tsum, inter, src_sum, ce_sum, n_valid, out);
}

// Round 8
// 226.708 us; speedup vs baseline: 1.0181x; 1.0181x over previous
//
#include <hip/hip_runtime.h>
#include <hip/hip_bf16.h>

// Problem constants (fixed by setup_inputs)
constexpr int B = 4, Q = 100, C = 40, Cp1 = 41, HW = 65536;
constexpr int NPIX = B * HW;          // 262144

// A-part: 512 blocks, 256 thr, 2 px/thread (float2), 5-plane load batches
constexpr int ATHR = 256, APX = 2;
constexpr int ABLKS = NPIX / (ATHR * APX);   // 512
constexpr int ASLOT = HW / (ATHR * APX);     // 128 A-blocks per batch image
constexpr int QU = 5;                         // 20 groups of 5 planes

// B-part: 8 chunks -> 3200 blocks, 256 thr, hist 40 KB -> 4 blocks/CU
constexpr int BCH = 8;
constexpr int BCPX = HW / BCH;               // 8192 px/block
constexpr int BIT = BCPX / (ATHR * 4);       // 8 iters

constexpr int GRID = ABLKS + B * Q * BCH;    // 3712

// Workspace layout (4-byte words) — verified R4 layout
//  [0, 16000)      counts  u32 [B][Q][C]
//  [16000, 16160)  tsum    u32 [B][C]
//  [16160, 32160)  inter   f32 [B][Q][C]
//  [32160, 32560)  src_sum f32 [B][Q]
//  [32560]         ce_sum  f32
//  [32561]         n_valid u32
constexpr int WS_WORDS = 32562;

__global__ void kZ(unsigned* __restrict__ ws, int n) {
    int i = blockIdx.x * blockDim.x + threadIdx.x;
    for (; i < n; i += gridDim.x * blockDim.x) ws[i] = 0u;
}

// ONE kernel, two independent phases selected by blockIdx (uniform branch):
//  A-part (blocks [0,512)):   pixel-major — argmax_q, sum-exp LSE, counts/tsum/ce.
//  B-part (blocks [512,3712)): (b,q)-major — sigmoid sums via per-thread LDS
//                              hist columns (bank = tid%32, conflict-free).
// No inter-phase dependency -> no barrier. Both read masks; 105 MB < 256 MB L3
// so the second toucher of each line should hit Infinity Cache.
__global__ __launch_bounds__(256, 4) void kBig(const float* __restrict__ masks,
                                               const int* __restrict__ targets,
                                               unsigned* __restrict__ counts,
                                               unsigned* __restrict__ tsum,
                                               float* __restrict__ ce_sum,
                                               unsigned* __restrict__ n_valid,
                                               float* __restrict__ inter,
                                               float* __restrict__ src_sum) {
    __shared__ float hist[C][ATHR];   // exactly 40 KB -> 4 blocks/CU
    int tid = threadIdx.x;
    int blk = blockIdx.x;

    if (blk < ABLKS) {
        // ---------- A-part ----------
        // alias tiny arrays into hist storage (A-part never uses hist)
        unsigned* ts_local = (unsigned*)&hist[0][0];   // words 0..39
        float*    cred     = &hist[0][64];             // words 64..67
        unsigned* vred     = (unsigned*)&hist[0][72];  // words 72..75

        int b = blk / ASLOT;
        int hw = (blk % ASLOT) * (ATHR * APX) + tid * APX;
        const float* mp = masks + (size_t)b * Q * HW + hw;
        int2 tg = *(const int2*)(targets + (size_t)b * HW + hw);
        int tgs[2] = {tg.x, tg.y};

        float m[2] = {-INFINITY, -INFINITY}, s[2] = {0.f, 0.f}, xt[2] = {0.f, 0.f};
        int amax[2] = {0, 0};

        for (int qq = 0; qq < Q; qq += QU) {
            float2 vv[QU];
            #pragma unroll
            for (int u = 0; u < QU; ++u)
                vv[u] = *(const float2*)(mp + (size_t)(qq + u) * HW);
            #pragma unroll
            for (int u = 0; u < QU; ++u) {
                int q = qq + u;
                float v[2] = {vv[u].x, vv[u].y};
                #pragma unroll
                for (int j = 0; j < 2; ++j) {
                    s[j] += __expf(v[j]);                    // |v|<=~6: f32-safe
                    amax[j] = (v[j] > m[j]) ? q : amax[j];   // strict >: first max
                    m[j] = fmaxf(m[j], v[j]);
                    xt[j] = (q == tgs[j]) ? v[j] : xt[j];
                }
            }
        }

        if (tid < C) ts_local[tid] = 0u;
        __syncthreads();

        float ce = 0.f;
        unsigned nv = 0;
        #pragma unroll
        for (int j = 0; j < 2; ++j) {
            if (tgs[j] != 255) {                             // valid; in [0,40)
                ce += __logf(s[j]) - xt[j];
                nv++;
                atomicAdd(&counts[((size_t)b * Q + amax[j]) * C + tgs[j]], 1u);
                atomicAdd(&ts_local[tgs[j]], 1u);
            }
        }
        for (int off = 32; off; off >>= 1) {
            ce += __shfl_xor(ce, off);
            nv += __shfl_xor(nv, off);
        }
        int lane = tid & 63, wave = tid >> 6;
        if (lane == 0) { cred[wave] = ce; vred[wave] = nv; }
        __syncthreads();   // covers ts_local atomics too
        if (tid == 0) {
            atomicAdd(ce_sum, cred[0] + cred[1] + cred[2] + cred[3]);
            atomicAdd(n_valid, vred[0] + vred[1] + vred[2] + vred[3]);
        }
        if (tid < C) {
            unsigned t = ts_local[tid];
            if (t) atomicAdd(&tsum[b * C + tid], t);
        }
    } else {
        // ---------- B-part ----------
        int r = blk - ABLKS;             // 0..3199
        int bq = r >> 3;
        int chunk = r & 7;
        int b = bq / Q;
        const float* mp = masks + (size_t)bq * HW + chunk * BCPX;
        const int* tp = targets + (size_t)b * HW + chunk * BCPX;

        #pragma unroll
        for (int c = 0; c < C; ++c) hist[c][tid] = 0.f;   // own column only

        float sacc = 0.f;
        #pragma unroll 2
        for (int it = 0; it < BIT; ++it) {                 // 8 iters * 1024 px
            int off = it * (ATHR * 4) + tid * 4;
            float4 x = *(const float4*)(mp + off);
            int4 tg = *(const int4*)(tp + off);
            float xs[4] = {x.x, x.y, x.z, x.w};
            int cs[4] = {tg.x, tg.y, tg.z, tg.w};
            #pragma unroll
            for (int j = 0; j < 4; ++j) {
                float sig = 1.f / (1.f + __expf(-xs[j]));
                sacc += sig;
                if ((unsigned)cs[j] < (unsigned)C) hist[cs[j]][tid] += sig;
            }
        }

        for (int off = 32; off; off >>= 1) sacc += __shfl_xor(sacc, off);
        int lane = tid & 63, wave = tid >> 6;
        if (lane == 0) atomicAdd(&src_sum[bq], sacc);

        __syncthreads();
        // wave w reduces 10 classes
        for (int c = wave * 10; c < wave * 10 + 10; ++c) {
            float h = hist[c][lane] + hist[c][lane + 64] + hist[c][lane + 128] + hist[c][lane + 192];
            for (int off = 32; off; off >>= 1) h += __shfl_xor(h, off);
            if (lane == 0) atomicAdd(&inter[(size_t)bq * C + c], h);
        }
    }
}

// Kernel C: finalize. Single block. f32 scalar out. (Verified R4.)
__global__ __launch_bounds__(512) void kC(const float* __restrict__ logits,
                                          const unsigned* __restrict__ counts,
                                          const unsigned* __restrict__ tsum,
                                          const float* __restrict__ inter,
                                          const float* __restrict__ src_sum,
                                          const float* __restrict__ ce_sum,
                                          const unsigned* __restrict__ n_valid,
                                          float* __restrict__ out) {
    int tid = threadIdx.x;
    __shared__ float dice_sum[C];
    __shared__ float wred[8];
    __shared__ float s_lce;
    if (tid < C) dice_sum[tid] = 0.f;

    float ce_acc = 0.f;
    for (int i = tid; i < B * Q; i += 512) {
        const unsigned* cnt = counts + (size_t)i * C;
        unsigned best = 0;
        int tc = C;
        #pragma unroll
        for (int c = 0; c < C; ++c) {
            unsigned v = cnt[c];
            if (v > best) { best = v; tc = c; }
        }
        if (tc != C) {
            const float* lg = logits + (size_t)i * Cp1;
            float mm = -INFINITY, xt = 0.f;
            #pragma unroll
            for (int c = 0; c < Cp1; ++c) {
                float v = lg[c];
                mm = fmaxf(mm, v);
                if (c == tc) xt = v;
            }
            float ss = 0.f;
            #pragma unroll
            for (int c = 0; c < Cp1; ++c) ss += __expf(lg[c] - mm);
            float nll = mm + __logf(ss) - xt;
            float p = __expf(-nll);
            float om = 1.f - p;
            ce_acc += om * om * nll;
        }
    }
    for (int off = 32; off; off >>= 1) ce_acc += __shfl_xor(ce_acc, off);
    if ((tid & 63) == 0) wred[tid >> 6] = ce_acc;
    __syncthreads();
    if (tid == 0) {
        float t = 0.f;
        for (int w = 0; w < 8; ++w) t += wred[w];
        s_lce = t;
    }

    for (int i = tid; i < B * Q * C; i += 512) {
        int bq = i / C, c = i - bq * C;
        float denom = src_sum[bq] + (float)tsum[(bq / Q) * C + c] + 1e-8f;
        atomicAdd(&dice_sum[c], 2.f * inter[i] / denom);
    }
    __syncthreads();

    if (tid == 0) {
        float dl = 0.f;
        for (int c = 0; c < C; ++c) {
            unsigned ts = tsum[c] + tsum[C + c] + tsum[2 * C + c] + tsum[3 * C + c];
            if (ts > 0) dl += 1.f - dice_sum[c] * (1.f / (B * Q));
        }
        dl *= (1.f / C);
        float ce_mask = ce_sum[0] / fmaxf((float)n_valid[0], 1.f);
        float lce = s_lce * (1.f / (B * Q));
        out[0] = 2.f * lce + 5.f * ce_mask + 5.f * dl;
    }
}

extern "C" void kernel_launch(void* const* d_in, const int* in_sizes, int n_in,
                              void* d_out, int out_size, void* d_ws, size_t ws_size,
                              hipStream_t stream) {
    const float* logits  = (const float*)d_in[0];   // [B,Q,41] f32
    const float* masks   = (const float*)d_in[1];   // [B,Q,H,W] f32
    const int*   targets = (const int*)d_in[2];     // [B,H,W] int32
    float* out = (float*)d_out;                     // f32 scalar

    unsigned* ws      = (unsigned*)d_ws;
    unsigned* counts  = ws;                         // 16000 u32
    unsigned* tsum    = ws + 16000;                 // 160 u32
    float*    inter   = (float*)(ws + 16160);       // 16000 f32
    float*    src_sum = (float*)(ws + 32160);       // 400 f32
    float*    ce_sum  = (float*)(ws + 32560);       // 1 f32
    unsigned* n_valid = ws + 32561;                 // 1 u32

    kZ<<<64, 256, 0, stream>>>(ws, WS_WORDS);
    kBig<<<GRID, ATHR, 0, stream>>>(masks, targets, counts, tsum, ce_sum, n_valid,
                                    inter, src_sum);
    kC<<<1, 512, 0, stream>>>(logits, counts, tsum, inter, src_sum, ce_sum, n_valid, out);
}